// Round 7
// baseline (72.258 us; speedup 1.0000x reference)
//
#include <hip/hip_runtime.h>
#include <cstdint>
#include <cstddef>

// Reference semantics: per-element fp32-rounded multiply, then a strictly
// sequential left-to-right fp32 add chain. FMA contraction changes low
// mantissa bits and flips output pulse bits -> keep contract OFF globally.
#pragma clang fp contract(off)

#define BATCH 256
#define IN_F  1024
#define OUT_F 1024

// ---------------------------------------------------------------------------
// decode: 32 pulse floats (0.0/1.0, MSB first) -> fp32 bit pattern
// ---------------------------------------------------------------------------
__device__ __forceinline__ uint32_t decode_bits(const float4* __restrict__ p) {
    uint32_t u = 0;
#pragma unroll
    for (int k = 0; k < 8; ++k) {
        float4 f = p[k];
        u = (u << 1) | ((__float_as_uint(f.x) >> 23) & 1u);
        u = (u << 1) | ((__float_as_uint(f.y) >> 23) & 1u);
        u = (u << 1) | ((__float_as_uint(f.z) >> 23) & 1u);
        u = (u << 1) | ((__float_as_uint(f.w) >> 23) & 1u);
    }
    return u;
}

// Fused decode: blocks [0,1024) decode x -> xf[B][IN]; blocks [1024,5120)
// decode w -> wt3 [IN/32][OUT][8 q][4 d] (pre-swizzled source layout for the
// gemm's global_load_lds staging; rule #21: linear LDS dest + swizzled src).
__global__ __launch_bounds__(256) void decode_kernel(const float* __restrict__ xp,
                                                     const float* __restrict__ wp,
                                                     float* __restrict__ xf,
                                                     float* __restrict__ wt3) {
    const int bid = blockIdx.x;
    const int tid = threadIdx.x;
    if (bid < (BATCH * IN_F) / 256) {
        int v = bid * 256 + tid;
        const float4* p = (const float4*)(xp + (size_t)v * 32);
        xf[v] = __uint_as_float(decode_bits(p));
    } else {
        int v = (bid - (BATCH * IN_F) / 256) * 256 + tid;   // v = o*IN + i
        int o = v >> 10;
        int i = v & (IN_F - 1);
        const float4* p = (const float4*)(wp + (size_t)v * 32);
        float val = __uint_as_float(decode_bits(p));
        size_t idx = (((((size_t)(i >> 5)) << 10) + o) * 8 + ((i >> 2) & 7)) * 4 + (i & 3);
        wt3[idx] = val;
    }
}

// ---------------------------------------------------------------------------
// GEMM: block = 256 threads = 4 waves; 64 o (lanes) x 8 b rows (wave wv
// handles rows wv and wv+4). Grid = 16 o-tiles x 32 b-tiles = 512 blocks
// = 2 blocks/CU (32 KB LDS each) so barrier/vmcnt drains overlap with the
// co-resident block's compute (R4/R6 residual: 1 lockstep block/CU).
// w staged in LDS per 64-i chunk (double-buffered, global_load_lds), bank-
// optimal layout per 32-i sub-chunk: [o=64][slot=8] float4, slot = q^(o&7).
// x delivered via v_readlane from one per-lane dword (lane = i within chunk).
// Strict left-to-right fp32 accumulation over i; mul then add, no FMA.
// acc starts at 0.0f: 0 + p0 == p0 bitwise for p0 != +-0 (holds for this
// data: |x*w| >= ~1e-12), so no first-iteration special case.
// ---------------------------------------------------------------------------
__global__ __launch_bounds__(256, 2) void gemm_encode_kernel(const float* __restrict__ xf,
                                                             const float* __restrict__ wt3,
                                                             float* __restrict__ out) {
#pragma clang fp contract(off)
    const int tid  = threadIdx.x;
    const int lane = tid & 63;
    const int wv   = tid >> 6;                     // 0..3
    const int ot   = blockIdx.x & 15;              // o-tile
    const int bt   = blockIdx.x >> 4;              // b-tile (0..31)
    const int o_g  = ot * 64 + lane;
    const int b0   = bt * 8;
    const int om   = lane & 7;

    __shared__ float4 wl[2][2][64][8];             // 32 KB: [buf][sc][o][slot]

    const float* __restrict__ xr0 = xf + ((size_t)(b0 + wv) << 10);
    const float* __restrict__ xr1 = xf + ((size_t)(b0 + wv + 4) << 10);

    // staging mapping (linear LDS dest): thread t covers o = h*32 + (t>>3),
    // physical slot s = t&7 holding content q = s ^ (o&7).
    const int o_lo = tid >> 3;                     // 0..31
    const int q_st = (tid & 7) ^ ((tid >> 3) & 7);

    auto stage = [&](int bb, int c) {
#pragma unroll
        for (int sc = 0; sc < 2; ++sc) {
            const int sc_g = c * 2 + sc;           // global 32-i sub-chunk
#pragma unroll
            for (int h = 0; h < 2; ++h) {
                const int o_st = h * 32 + o_lo;
                size_t dw = (((((size_t)sc_g) << 10) + (ot * 64 + o_st)) * 8 + q_st) * 4;
                const char* g = (const char*)(wt3 + dw);
                char* d = (char*)(&wl[bb][sc][0][0]) + h * 4096 + tid * 16;
                __builtin_amdgcn_global_load_lds(
                    (const __attribute__((address_space(1))) void*)g,
                    (__attribute__((address_space(3))) void*)d, 16, 0, 0);
            }
        }
    };

    float acc0 = 0.0f, acc1 = 0.0f;

    // xa0/xa1 hold x[row][c*64 + lane] (lane = i offset within the chunk).
    auto compute = [&](int bb, float xa0, float xa1) {
#pragma unroll
        for (int sc = 0; sc < 2; ++sc) {
            float4 w4[8];
#pragma unroll
            for (int q = 0; q < 8; ++q) w4[q] = wl[bb][sc][lane][q ^ om];
#pragma unroll
            for (int q = 0; q < 8; ++q) {
                const float wq[4] = {w4[q].x, w4[q].y, w4[q].z, w4[q].w};
#pragma unroll
                for (int d = 0; d < 4; ++d) {
                    const int ll = sc * 32 + q * 4 + d;    // literal lane index
                    float x0 = __uint_as_float(
                        __builtin_amdgcn_readlane(__float_as_uint(xa0), ll));
                    float x1 = __uint_as_float(
                        __builtin_amdgcn_readlane(__float_as_uint(xa1), ll));
                    acc0 = acc0 + (x0 * wq[d]);
                    acc1 = acc1 + (x1 * wq[d]);
                }
            }
        }
    };

    // prologue: stage chunk 0 (w) and load chunk 0's x dwords
    stage(0, 0);
    float xa0 = xr0[lane];
    float xa1 = xr1[lane];
    __syncthreads();                                // drains vmcnt before use

    int cur = 0;
#pragma unroll 1
    for (int c = 0; c < 16; ++c) {
        float na0 = 0.f, na1 = 0.f;
        if (c < 15) {
            stage(cur ^ 1, c + 1);                  // issue next w-chunk loads
            na0 = xr0[(c + 1) * 64 + lane];         // and next x dwords
            na1 = xr1[(c + 1) * 64 + lane];
        }
        compute(cur, xa0, xa1);
        __syncthreads();                            // vmcnt+lgkm drain + barrier
        xa0 = na0; xa1 = na1; cur ^= 1;
    }

    // ---- encode both accumulators back to 32 pulse floats ----
    const float accs[2] = {acc0, acc1};
#pragma unroll
    for (int r = 0; r < 2; ++r) {
        uint32_t u = __float_as_uint(accs[r]);
        int b = b0 + wv + r * 4;
        float4* dstp = (float4*)(out + (((size_t)b << 10) + o_g) * 32);
#pragma unroll
        for (int k = 0; k < 8; ++k) {
            float4 f;
            f.x = (float)((u >> (31 - 4 * k)) & 1u);
            f.y = (float)((u >> (30 - 4 * k)) & 1u);
            f.z = (float)((u >> (29 - 4 * k)) & 1u);
            f.w = (float)((u >> (28 - 4 * k)) & 1u);
            dstp[k] = f;
        }
    }
}

extern "C" void kernel_launch(void* const* d_in, const int* in_sizes, int n_in,
                              void* d_out, int out_size, void* d_ws, size_t ws_size,
                              hipStream_t stream) {
    const float* x_pulses = (const float*)d_in[0];   // [B, IN, 32]
    const float* w_pulses = (const float*)d_in[1];   // [OUT, IN, 32]
    float* out = (float*)d_out;                      // [B, OUT, 32]

    float* xf  = (float*)d_ws;                       // 1 MB
    float* wt3 = xf + (size_t)BATCH * IN_F;          // 4 MB

    decode_kernel<<<(BATCH * IN_F + OUT_F * IN_F) / 256, 256, 0, stream>>>(
        x_pulses, w_pulses, xf, wt3);
    gemm_encode_kernel<<<512, 256, 0, stream>>>(xf, wt3, out);
}